// Round 2
// baseline (2821.294 us; speedup 1.0000x reference)
//
#include <hip/hip_runtime.h>

#define C_CH 4
#define F_INN 64
#define F_OUTT 64
#define CF 256  // C_CH * F_OUTT
#define NODES_PER_BLOCK 16

// ---------------- degree / normalization ----------------

__global__ void deg_init_kernel(float* __restrict__ deg, int n) {
    int i = blockIdx.x * blockDim.x + threadIdx.x;
    if (i < n) deg[i] = 1.0f;  // self-loop contributes weight 1 to every node
}

__global__ void deg_accum_kernel(const int* __restrict__ col,
                                 const float* __restrict__ ew,
                                 float* __restrict__ deg, int E) {
    int e = blockIdx.x * blockDim.x + threadIdx.x;
    if (e < E) unsafeAtomicAdd(&deg[col[e]], ew[e]);
}

__global__ void dinv_kernel(float* __restrict__ deg, int n) {
    int i = blockIdx.x * blockDim.x + threadIdx.x;
    if (i < n) {
        float d = deg[i];
        deg[i] = (d > 0.0f) ? rsqrtf(d) : 0.0f;
    }
}

// ---------------- per-channel linear + self-loop + bias ----------------
// out[n,c,f] = xw[n,c,f] * dinv[n]^2 + b[c,f];  xw[n,c,f] = sum_k x[n,c,k]*W[c,k,f]

__global__ __launch_bounds__(256) void xw_kernel(const float* __restrict__ x,
                                                 const float* __restrict__ W,
                                                 const float* __restrict__ b,
                                                 const float* __restrict__ dinv,
                                                 float* __restrict__ xw,
                                                 float* __restrict__ out, int n) {
    __shared__ float Wl[C_CH * F_INN * F_OUTT];  // 64 KB
    int t = threadIdx.x;

    // cooperative load of W into LDS: 16384 floats = 4096 float4, 256 threads -> 16 each
    const float4* W4 = reinterpret_cast<const float4*>(W);
    float4* Wl4 = reinterpret_cast<float4*>(Wl);
#pragma unroll
    for (int i = 0; i < 16; ++i) Wl4[t + 256 * i] = W4[t + 256 * i];
    __syncthreads();

    int c = t >> 6;       // channel 0..3
    int f = t & 63;       // output feature 0..63
    int n0 = blockIdx.x * NODES_PER_BLOCK;

    for (int ni = 0; ni < NODES_PER_BLOCK; ++ni) {
        int node = n0 + ni;
        if (node >= n) break;
        const float* __restrict__ xr = x + (size_t)node * CF + c * F_INN;
        const float* __restrict__ Wc = Wl + (c * F_INN) * F_OUTT + f;
        float acc = 0.0f;
#pragma unroll
        for (int k = 0; k < F_INN; ++k) {
            acc = fmaf(xr[k], Wc[k * F_OUTT], acc);
        }
        float di = dinv[node];
        size_t idx = (size_t)node * CF + c * F_OUTT + f;
        xw[idx] = acc;
        out[idx] = fmaf(acc, di * di, b[c * F_OUTT + f]);
    }
}

// ---------------- edge scatter: one wave (64 lanes) per edge ----------------
// out[col, :] += xw[row, :] * (dinv[row] * ew * dinv[col]);  256 floats = 64 lanes x float4

__global__ __launch_bounds__(256) void edge_kernel(const int* __restrict__ row,
                                                   const int* __restrict__ col,
                                                   const float* __restrict__ ew,
                                                   const float* __restrict__ dinv,
                                                   const float* __restrict__ xw,
                                                   float* __restrict__ out, int E) {
    int gwid = (int)((blockIdx.x * 256u + threadIdx.x) >> 6);
    int lane = threadIdx.x & 63;
    if (gwid >= E) return;
    int r = row[gwid];
    int cc = col[gwid];
    float nrm = dinv[r] * ew[gwid] * dinv[cc];
    const float4 v = *reinterpret_cast<const float4*>(xw + (size_t)r * CF + lane * 4);
    float* o = out + (size_t)cc * CF + lane * 4;
    unsafeAtomicAdd(o + 0, v.x * nrm);
    unsafeAtomicAdd(o + 1, v.y * nrm);
    unsafeAtomicAdd(o + 2, v.z * nrm);
    unsafeAtomicAdd(o + 3, v.w * nrm);
}

// ---------------- launch ----------------

extern "C" void kernel_launch(void* const* d_in, const int* in_sizes, int n_in,
                              void* d_out, int out_size, void* d_ws, size_t ws_size,
                              hipStream_t stream) {
    const float* x  = (const float*)d_in[0];
    const int*   ei = (const int*)d_in[1];
    const float* ew = (const float*)d_in[2];
    const float* W  = (const float*)d_in[3];
    const float* b  = (const float*)d_in[4];
    float* out = (float*)d_out;

    int n = in_sizes[0] / (C_CH * F_INN);  // 50000
    int E = in_sizes[2];                    // 800000

    const int* row = ei;       // edge_index[0] = source
    const int* col = ei + E;   // edge_index[1] = target

    // workspace layout: deg/dinv [n] floats, then xw [n*CF] floats (256B aligned)
    float* deg = (float*)d_ws;
    size_t dinv_bytes = ((size_t)n * sizeof(float) + 255) & ~(size_t)255;
    float* xw = (float*)((char*)d_ws + dinv_bytes);

    deg_init_kernel<<<(n + 255) / 256, 256, 0, stream>>>(deg, n);
    deg_accum_kernel<<<(E + 255) / 256, 256, 0, stream>>>(col, ew, deg, E);
    dinv_kernel<<<(n + 255) / 256, 256, 0, stream>>>(deg, n);

    xw_kernel<<<(n + NODES_PER_BLOCK - 1) / NODES_PER_BLOCK, 256, 0, stream>>>(
        x, W, b, deg, xw, out, n);

    edge_kernel<<<(E + 3) / 4, 256, 0, stream>>>(row, col, ew, deg, xw, out, E);
}

// Round 3
// 367.815 us; speedup vs baseline: 7.6704x; 7.6704x over previous
//
#include <hip/hip_runtime.h>

#define C_CH 4
#define F_INN 64
#define F_OUTT 64
#define CF 256  // C_CH * F_OUTT
#define NODES_PER_BLOCK 16
#define SCAN_TILE 1024

// ---------------- init: deg=1 (self loop), cnt=0 ----------------
__global__ void init_kernel(float* __restrict__ deg, int* __restrict__ cnt, int n) {
    int i = blockIdx.x * blockDim.x + threadIdx.x;
    if (i < n) { deg[i] = 1.0f; cnt[i] = 0; }
}

// ---------------- histogram: edge count + weighted degree per target ----------------
__global__ void hist_kernel(const int* __restrict__ col,
                            const float* __restrict__ ew,
                            float* __restrict__ deg, int* __restrict__ cnt, int E) {
    int e = blockIdx.x * blockDim.x + threadIdx.x;
    if (e < E) {
        int d = col[e];
        atomicAdd(&cnt[d], 1);
        unsafeAtomicAdd(&deg[d], ew[e]);
    }
}

__global__ void dinv_kernel(float* __restrict__ deg, int n) {
    int i = blockIdx.x * blockDim.x + threadIdx.x;
    if (i < n) {
        float d = deg[i];
        deg[i] = (d > 0.0f) ? rsqrtf(d) : 0.0f;
    }
}

// ---------------- exclusive scan of cnt -> offs (3 kernels) ----------------
__global__ __launch_bounds__(SCAN_TILE) void scan1_kernel(const int* __restrict__ cnt,
                                                          int* __restrict__ offs,
                                                          int* __restrict__ blk, int n) {
    __shared__ int s[SCAN_TILE];
    int t = threadIdx.x;
    int g = blockIdx.x * SCAN_TILE + t;
    int v = (g < n) ? cnt[g] : 0;
    s[t] = v;
    __syncthreads();
    for (int d = 1; d < SCAN_TILE; d <<= 1) {
        int x = (t >= d) ? s[t - d] : 0;
        __syncthreads();
        s[t] += x;
        __syncthreads();
    }
    if (g < n) offs[g] = s[t] - v;  // exclusive
    if (t == SCAN_TILE - 1) blk[blockIdx.x] = s[t];
}

__global__ void scan2_kernel(int* __restrict__ blk, int* __restrict__ offs, int nb, int n) {
    if (threadIdx.x == 0 && blockIdx.x == 0) {
        int run = 0;
        for (int i = 0; i < nb; ++i) { int v = blk[i]; blk[i] = run; run += v; }
        offs[n] = run;  // == E
    }
}

__global__ void scan3_kernel(int* __restrict__ offs, const int* __restrict__ blk,
                             int* __restrict__ cnt, int n) {
    int g = blockIdx.x * blockDim.x + threadIdx.x;
    if (g < n) {
        offs[g] += blk[g >> 10];
        cnt[g] = 0;  // reuse as running cursor in scatter
    }
}

// ---------------- scatter edges into CSR buckets: (src, norm) pairs ----------------
__global__ void scatter_kernel(const int* __restrict__ row, const int* __restrict__ col,
                               const float* __restrict__ ew, const float* __restrict__ dinv,
                               const int* __restrict__ offs, int* __restrict__ cnt,
                               int2* __restrict__ edata, int E) {
    int e = blockIdx.x * blockDim.x + threadIdx.x;
    if (e < E) {
        int r = row[e];
        int d = col[e];
        float nrm = dinv[r] * ew[e] * dinv[d];
        int pos = offs[d] + atomicAdd(&cnt[d], 1);
        edata[pos] = make_int2(r, __float_as_int(nrm));
    }
}

// ---------------- per-channel linear: xw[n,c,f] = sum_k x[n,c,k]*W[c,k,f] ----------------
__global__ __launch_bounds__(256) void xw_kernel(const float* __restrict__ x,
                                                 const float* __restrict__ W,
                                                 float* __restrict__ xw, int n) {
    __shared__ float Wl[C_CH * F_INN * F_OUTT];  // 64 KB
    int t = threadIdx.x;
    const float4* W4 = reinterpret_cast<const float4*>(W);
    float4* Wl4 = reinterpret_cast<float4*>(Wl);
#pragma unroll
    for (int i = 0; i < 16; ++i) Wl4[t + 256 * i] = W4[t + 256 * i];
    __syncthreads();

    int c = t >> 6;
    int f = t & 63;
    int n0 = blockIdx.x * NODES_PER_BLOCK;

    for (int ni = 0; ni < NODES_PER_BLOCK; ++ni) {
        int node = n0 + ni;
        if (node >= n) break;
        const float* __restrict__ xr = x + (size_t)node * CF + c * F_INN;
        const float* __restrict__ Wc = Wl + (c * F_INN) * F_OUTT + f;
        float acc = 0.0f;
#pragma unroll
        for (int k = 0; k < F_INN; ++k) acc = fmaf(xr[k], Wc[k * F_OUTT], acc);
        xw[(size_t)node * CF + c * F_OUTT + f] = acc;
    }
}

// ---------------- gather: one wave per destination node, no atomics ----------------
__global__ __launch_bounds__(256) void gather_kernel(const int* __restrict__ offs,
                                                     const int2* __restrict__ edata,
                                                     const float* __restrict__ dinv,
                                                     const float* __restrict__ xw,
                                                     const float* __restrict__ b,
                                                     float* __restrict__ out, int n) {
    int v = (int)((blockIdx.x * 256u + threadIdx.x) >> 6);
    int lane = threadIdx.x & 63;
    if (v >= n) return;

    int beg = offs[v];
    int end = offs[v + 1];
    float di = dinv[v];

    const float4 xv = *reinterpret_cast<const float4*>(xw + (size_t)v * CF + lane * 4);
    const float4 bv = *reinterpret_cast<const float4*>(b + lane * 4);
    float s = di * di;
    float4 acc;
    acc.x = fmaf(xv.x, s, bv.x);
    acc.y = fmaf(xv.y, s, bv.y);
    acc.z = fmaf(xv.z, s, bv.z);
    acc.w = fmaf(xv.w, s, bv.w);

    for (int j = beg; j < end; ++j) {
        int2 ed = edata[j];               // lane-uniform broadcast load
        int r = ed.x;
        float nrm = __int_as_float(ed.y);
        const float4 xr = *reinterpret_cast<const float4*>(xw + (size_t)r * CF + lane * 4);
        acc.x = fmaf(xr.x, nrm, acc.x);
        acc.y = fmaf(xr.y, nrm, acc.y);
        acc.z = fmaf(xr.z, nrm, acc.z);
        acc.w = fmaf(xr.w, nrm, acc.w);
    }
    *reinterpret_cast<float4*>(out + (size_t)v * CF + lane * 4) = acc;
}

// ---------------- launch ----------------
extern "C" void kernel_launch(void* const* d_in, const int* in_sizes, int n_in,
                              void* d_out, int out_size, void* d_ws, size_t ws_size,
                              hipStream_t stream) {
    const float* x  = (const float*)d_in[0];
    const int*   ei = (const int*)d_in[1];
    const float* ew = (const float*)d_in[2];
    const float* W  = (const float*)d_in[3];
    const float* b  = (const float*)d_in[4];
    float* out = (float*)d_out;

    int n = in_sizes[0] / (C_CH * F_INN);  // 50000
    int E = in_sizes[2];                    // 800000

    const int* row = ei;       // source
    const int* col = ei + E;   // target

    // workspace layout (256B-aligned chunks)
    auto align_up = [](size_t v) { return (v + 255) & ~(size_t)255; };
    char* p = (char*)d_ws;
    float* deg  = (float*)p;                 p += align_up((size_t)n * 4);
    int*   cnt  = (int*)p;                   p += align_up((size_t)n * 4);
    int*   offs = (int*)p;                   p += align_up(((size_t)n + 1) * 4);
    int*   blk  = (int*)p;                   p += align_up(64 * 4);
    int2*  edata= (int2*)p;                  p += align_up((size_t)E * 8);
    float* xw   = (float*)p;                 // n*CF floats

    int nb = (n + SCAN_TILE - 1) / SCAN_TILE;

    init_kernel<<<(n + 255) / 256, 256, 0, stream>>>(deg, cnt, n);
    hist_kernel<<<(E + 255) / 256, 256, 0, stream>>>(col, ew, deg, cnt, E);
    dinv_kernel<<<(n + 255) / 256, 256, 0, stream>>>(deg, n);

    scan1_kernel<<<nb, SCAN_TILE, 0, stream>>>(cnt, offs, blk, n);
    scan2_kernel<<<1, 64, 0, stream>>>(blk, offs, nb, n);
    scan3_kernel<<<(n + 255) / 256, 256, 0, stream>>>(offs, blk, cnt, n);

    scatter_kernel<<<(E + 255) / 256, 256, 0, stream>>>(row, col, ew, deg, offs, cnt, edata, E);

    xw_kernel<<<(n + NODES_PER_BLOCK - 1) / NODES_PER_BLOCK, 256, 0, stream>>>(x, W, xw, n);

    gather_kernel<<<(n * 64 + 255) / 256, 256, 0, stream>>>(offs, edata, deg, xw, b, out, n);
}

// Round 4
// 367.688 us; speedup vs baseline: 7.6731x; 1.0003x over previous
//
#include <hip/hip_runtime.h>

#define C_CH 4
#define F_INN 64
#define F_OUTT 64
#define CF 256  // C_CH * F_OUTT
#define SCAN_TILE 1024
#define XW_NB 32  // nodes per block in xw_kernel

// ---------------- init: deg=1 (self loop), cnt=0 ----------------
__global__ void init_kernel(float* __restrict__ deg, int* __restrict__ cnt, int n) {
    int i = blockIdx.x * blockDim.x + threadIdx.x;
    if (i < n) { deg[i] = 1.0f; cnt[i] = 0; }
}

// ---------------- histogram: edge count + weighted degree per target ----------------
__global__ void hist_kernel(const int* __restrict__ col,
                            const float* __restrict__ ew,
                            float* __restrict__ deg, int* __restrict__ cnt, int E) {
    int e = blockIdx.x * blockDim.x + threadIdx.x;
    if (e < E) {
        int d = col[e];
        atomicAdd(&cnt[d], 1);
        unsafeAtomicAdd(&deg[d], ew[e]);
    }
}

// ---------------- exclusive scan of cnt -> offs (3 kernels) ----------------
__global__ __launch_bounds__(SCAN_TILE) void scan1_kernel(const int* __restrict__ cnt,
                                                          int* __restrict__ offs,
                                                          int* __restrict__ blk, int n) {
    __shared__ int s[SCAN_TILE];
    int t = threadIdx.x;
    int g = blockIdx.x * SCAN_TILE + t;
    int v = (g < n) ? cnt[g] : 0;
    s[t] = v;
    __syncthreads();
    for (int d = 1; d < SCAN_TILE; d <<= 1) {
        int x = (t >= d) ? s[t - d] : 0;
        __syncthreads();
        s[t] += x;
        __syncthreads();
    }
    if (g < n) offs[g] = s[t] - v;  // exclusive
    if (t == SCAN_TILE - 1) blk[blockIdx.x] = s[t];
}

__global__ void scan2_kernel(int* __restrict__ blk, int* __restrict__ offs, int nb, int n) {
    if (threadIdx.x == 0 && blockIdx.x == 0) {
        int run = 0;
        for (int i = 0; i < nb; ++i) { int v = blk[i]; blk[i] = run; run += v; }
        offs[n] = run;  // == E
    }
}

__global__ void scan3_kernel(int* __restrict__ offs, const int* __restrict__ blk,
                             int* __restrict__ cnt, int n) {
    int g = blockIdx.x * blockDim.x + threadIdx.x;
    if (g < n) {
        offs[g] += blk[g >> 10];
        cnt[g] = 0;  // reuse as running cursor in scatter
    }
}

// ---------------- scatter edges into CSR buckets: (src, norm) pairs ----------------
__global__ void scatter_kernel(const int* __restrict__ row, const int* __restrict__ col,
                               const float* __restrict__ ew, const float* __restrict__ deg,
                               const int* __restrict__ offs, int* __restrict__ cnt,
                               int2* __restrict__ edata, int E) {
    int e = blockIdx.x * blockDim.x + threadIdx.x;
    if (e < E) {
        int r = row[e];
        int d = col[e];
        float nrm = rsqrtf(deg[r]) * ew[e] * rsqrtf(deg[d]);
        int pos = offs[d] + atomicAdd(&cnt[d], 1);
        edata[pos] = make_int2(r, __float_as_int(nrm));
    }
}

// ---------------- per-channel linear: W in registers, x row broadcast ----------------
// One wave per (node-chunk, channel). Lane f holds W[c][:,f] in 64 VGPRs.
__global__ __launch_bounds__(256) void xw_kernel(const float* __restrict__ x,
                                                 const float* __restrict__ W,
                                                 float* __restrict__ xw, int n) {
    int c = threadIdx.x >> 6;    // wave index == channel
    int lane = threadIdx.x & 63; // output feature f

    // W[c][k][f], k = 0..63 -> 64 coalesced scalar loads (256 B / wave / load)
    float wr[F_INN];
    const float* __restrict__ Wc = W + c * (F_INN * F_OUTT) + lane;
#pragma unroll
    for (int k = 0; k < F_INN; ++k) wr[k] = Wc[k * F_OUTT];

    int n0 = blockIdx.x * XW_NB;
    int nend = min(n0 + XW_NB, n);
    for (int node = n0; node < nend; ++node) {
        // x row for (node, c): 16 wave-uniform float4 broadcast loads
        const float4* __restrict__ xr =
            reinterpret_cast<const float4*>(x + (size_t)node * CF + c * F_INN);
        float acc = 0.0f;
#pragma unroll
        for (int q = 0; q < 16; ++q) {
            float4 xv = xr[q];
            acc = fmaf(xv.x, wr[4 * q + 0], acc);
            acc = fmaf(xv.y, wr[4 * q + 1], acc);
            acc = fmaf(xv.z, wr[4 * q + 2], acc);
            acc = fmaf(xv.w, wr[4 * q + 3], acc);
        }
        xw[(size_t)node * CF + c * F_OUTT + lane] = acc;  // coalesced 256 B store
    }
}

// ---------------- gather: one wave per destination node, no atomics ----------------
__global__ __launch_bounds__(256) void gather_kernel(const int* __restrict__ offs,
                                                     const int2* __restrict__ edata,
                                                     const float* __restrict__ deg,
                                                     const float* __restrict__ xw,
                                                     const float* __restrict__ b,
                                                     float* __restrict__ out, int n) {
    int v = (int)((blockIdx.x * 256u + threadIdx.x) >> 6);
    int lane = threadIdx.x & 63;
    if (v >= n) return;

    int beg = offs[v];
    int end = offs[v + 1];
    float di = rsqrtf(deg[v]);

    const float4 xv = *reinterpret_cast<const float4*>(xw + (size_t)v * CF + lane * 4);
    const float4 bv = *reinterpret_cast<const float4*>(b + lane * 4);
    float s = di * di;
    float4 acc;
    acc.x = fmaf(xv.x, s, bv.x);
    acc.y = fmaf(xv.y, s, bv.y);
    acc.z = fmaf(xv.z, s, bv.z);
    acc.w = fmaf(xv.w, s, bv.w);

    int j = beg;
    int e4 = beg + ((end - beg) & ~3);
    for (; j < e4; j += 4) {
        // 4 independent broadcast edge loads + 4 independent float4 gathers in flight
        int2 e0 = edata[j + 0];
        int2 e1 = edata[j + 1];
        int2 e2 = edata[j + 2];
        int2 e3 = edata[j + 3];
        const float4 x0 = *reinterpret_cast<const float4*>(xw + (size_t)e0.x * CF + lane * 4);
        const float4 x1 = *reinterpret_cast<const float4*>(xw + (size_t)e1.x * CF + lane * 4);
        const float4 x2 = *reinterpret_cast<const float4*>(xw + (size_t)e2.x * CF + lane * 4);
        const float4 x3 = *reinterpret_cast<const float4*>(xw + (size_t)e3.x * CF + lane * 4);
        float n0 = __int_as_float(e0.y), n1 = __int_as_float(e1.y);
        float n2 = __int_as_float(e2.y), n3 = __int_as_float(e3.y);
        acc.x = fmaf(x0.x, n0, acc.x); acc.y = fmaf(x0.y, n0, acc.y);
        acc.z = fmaf(x0.z, n0, acc.z); acc.w = fmaf(x0.w, n0, acc.w);
        acc.x = fmaf(x1.x, n1, acc.x); acc.y = fmaf(x1.y, n1, acc.y);
        acc.z = fmaf(x1.z, n1, acc.z); acc.w = fmaf(x1.w, n1, acc.w);
        acc.x = fmaf(x2.x, n2, acc.x); acc.y = fmaf(x2.y, n2, acc.y);
        acc.z = fmaf(x2.z, n2, acc.z); acc.w = fmaf(x2.w, n2, acc.w);
        acc.x = fmaf(x3.x, n3, acc.x); acc.y = fmaf(x3.y, n3, acc.y);
        acc.z = fmaf(x3.z, n3, acc.z); acc.w = fmaf(x3.w, n3, acc.w);
    }
    for (; j < end; ++j) {
        int2 ed = edata[j];
        float nrm = __int_as_float(ed.y);
        const float4 xr = *reinterpret_cast<const float4*>(xw + (size_t)ed.x * CF + lane * 4);
        acc.x = fmaf(xr.x, nrm, acc.x);
        acc.y = fmaf(xr.y, nrm, acc.y);
        acc.z = fmaf(xr.z, nrm, acc.z);
        acc.w = fmaf(xr.w, nrm, acc.w);
    }
    *reinterpret_cast<float4*>(out + (size_t)v * CF + lane * 4) = acc;
}

// ---------------- launch ----------------
extern "C" void kernel_launch(void* const* d_in, const int* in_sizes, int n_in,
                              void* d_out, int out_size, void* d_ws, size_t ws_size,
                              hipStream_t stream) {
    const float* x  = (const float*)d_in[0];
    const int*   ei = (const int*)d_in[1];
    const float* ew = (const float*)d_in[2];
    const float* W  = (const float*)d_in[3];
    const float* b  = (const float*)d_in[4];
    float* out = (float*)d_out;

    int n = in_sizes[0] / (C_CH * F_INN);  // 50000
    int E = in_sizes[2];                    // 800000

    const int* row = ei;       // source
    const int* col = ei + E;   // target

    // workspace layout (256B-aligned chunks)
    auto align_up = [](size_t v) { return (v + 255) & ~(size_t)255; };
    char* p = (char*)d_ws;
    float* deg  = (float*)p;                 p += align_up((size_t)n * 4);
    int*   cnt  = (int*)p;                   p += align_up((size_t)n * 4);
    int*   offs = (int*)p;                   p += align_up(((size_t)n + 1) * 4);
    int*   blk  = (int*)p;                   p += align_up(64 * 4);
    int2*  edata= (int2*)p;                  p += align_up((size_t)E * 8);
    float* xw   = (float*)p;                 // n*CF floats

    int nb = (n + SCAN_TILE - 1) / SCAN_TILE;

    init_kernel<<<(n + 255) / 256, 256, 0, stream>>>(deg, cnt, n);
    hist_kernel<<<(E + 255) / 256, 256, 0, stream>>>(col, ew, deg, cnt, E);

    scan1_kernel<<<nb, SCAN_TILE, 0, stream>>>(cnt, offs, blk, n);
    scan2_kernel<<<1, 64, 0, stream>>>(blk, offs, nb, n);
    scan3_kernel<<<(n + 255) / 256, 256, 0, stream>>>(offs, blk, cnt, n);

    scatter_kernel<<<(E + 255) / 256, 256, 0, stream>>>(row, col, ew, deg, offs, cnt, edata, E);

    xw_kernel<<<(n + XW_NB - 1) / XW_NB, 256, 0, stream>>>(x, W, xw, n);

    gather_kernel<<<(n * 64 + 255) / 256, 256, 0, stream>>>(offs, edata, deg, xw, b, out, n);
}